// Round 6
// baseline (90.462 us; speedup 1.0000x reference)
//
#include <hip/hip_runtime.h>
#include <hip/hip_bf16.h>
#include <stdint.h>

// Problem constants (fixed by the reference)
#define P 2048       // D_STATE
#define HN 64        // D_INPUT
#define L 16384      // kernel_size
#define KQ 4         // K split across blocks (k-quarters)
#define NT 8         // tiles per block (32 cols each -> 256 cols/block)
#define KTWV 4       // kt steps per wave (32 kt per quarter / 8 waves)

typedef __bf16 bf16_t;
typedef bf16_t bf16x8 __attribute__((ext_vector_type(8)));
typedef float f32x16 __attribute__((ext_vector_type(16)));

__device__ __forceinline__ float2 cmul(float2 a, float2 b) {
    return make_float2(a.x * b.x - a.y * b.y, a.x * b.y + a.y * b.x);
}

// Complex multiply in 2 VALU via packed-f32 (VOP3P).
// t = (ax*bx, ay*bx);  r = (-ay*by + t.lo, ax*by + t.hi) = cmul(a,b)
__device__ __forceinline__ float2 cmul_pk(float2 a, float2 b) {
    float2 t, r;
    asm("v_pk_mul_f32 %0, %1, %2 op_sel:[0,0] op_sel_hi:[1,0]"
        : "=v"(t) : "v"(a), "v"(b));
    asm("v_pk_fma_f32 %0, %1, %2, %3 op_sel:[1,1,0] op_sel_hi:[0,1,1] neg_lo:[1,0,0]"
        : "=v"(r) : "v"(a), "v"(b), "v"(t));
    return r;
}

__device__ __forceinline__ uint32_t packbf(float2 v) {
    union { __hip_bfloat162 v; uint32_t u; } cv;
    cv.v = __float22bfloat162_rn(make_float2(v.x, v.y));
    return cv.u;
}

// ---------------------------------------------------------------------------
// Prep: (a) W in bf16 32x32-MFMA A-fragment order: granule gid =
// ((kt*2+q)*2+mt)*64+lane holds A[m=mt*32+(lane&31)][k-run], p-run =
// kt*16 + q*8 + (lane>>5)*4, elements (W_re, -W_im) pairs (k=2p, 2p+1).
// (b) Tcol[p*32 + lc] = A_p^lc (float2), lc in [0,32) — block-invariant.
// (c) a32[p] = A_p^32.
// (d) abase[j*P + p] = A_p^(64j), j in [0,256) — binary exponentiation.
// (e) zero out (main accumulates into it with atomics).
__global__ void mv_prep(const float* __restrict__ Win,
                        const float* __restrict__ Ain,
                        uint4* __restrict__ wexp,
                        float2* __restrict__ tcol,
                        float2* __restrict__ a32,
                        float2* __restrict__ abase,
                        float4* __restrict__ outz) {
    int gid = blockIdx.x * 256 + threadIdx.x;   // 32768
    {   // wexp
        int lane = gid & 63;
        int mt = (gid >> 6) & 1;
        int q = (gid >> 7) & 1;
        int kt = gid >> 8;
        int m = mt * 32 + (lane & 31);
        int p0 = kt * 16 + q * 8 + (lane >> 5) * 4;
        const float4* wp = (const float4*)(Win + (size_t)(m * P + p0) * 2);
        float4 f0 = wp[0], f1 = wp[1];
        float re[4] = {f0.x, f0.z, f1.x, f1.z};
        float im[4] = {f0.y, f0.w, f1.y, f1.w};
        uint32_t o[4];
#pragma unroll
        for (int j = 0; j < 4; ++j)
            o[j] = packbf(make_float2(re[j], -im[j]));
        wexp[gid] = make_uint4(o[0], o[1], o[2], o[3]);
    }
    {   // Tcol: thread handles p = gid>>4, lc = 2*(gid&15) and lc+1
        int p = gid >> 4;
        int e = gid & 15;                      // lc/2
        float2 a = *(const float2*)(Ain + 2 * p);
        float2 a2 = cmul(a, a);
        float2 r = make_float2(1.f, 0.f);
        float2 sq = a2;
#pragma unroll
        for (int b = 0; b < 4; ++b) {
            if ((e >> b) & 1) r = cmul(r, sq);
            sq = cmul(sq, sq);
        }
        float2 ro = cmul(r, a);
        tcol[(size_t)p * 32 + 2 * e] = r;       // A^(2e)
        tcol[(size_t)p * 32 + 2 * e + 1] = ro;  // A^(2e+1)
        if (e == 15) a32[p] = cmul(ro, a);      // A^32
    }
    {   // abase: thread handles p = gid&2047, j in [16*(gid>>11), +16)
        int p = gid & 2047;
        int j16 = gid >> 11;                   // 0..15
        float2 a = *(const float2*)(Ain + 2 * p);
        float2 s = cmul(a, a);                 // A^2
#pragma unroll
        for (int i = 0; i < 5; ++i) s = cmul(s, s);   // A^64
        float2 a64v = s;
        float2 t1k = a64v;
#pragma unroll
        for (int i = 0; i < 4; ++i) t1k = cmul(t1k, t1k);  // A^1024
        float2 r = make_float2(1.f, 0.f);
        float2 sq = t1k;
#pragma unroll
        for (int b = 0; b < 4; ++b) {          // r = (A^1024)^j16
            if ((j16 >> b) & 1) r = cmul(r, sq);
            sq = cmul(sq, sq);
        }
        float2* ab = abase + (size_t)(j16 * 16) * P + p;
#pragma unroll
        for (int i = 0; i < 16; ++i) {
            ab[(size_t)i * P] = r;             // A^(64*(j16*16+i))
            r = cmul(r, a64v);
        }
    }
    {   // zero out: 1M floats = 262144 float4 = 8 x 32768
        float4 z = make_float4(0.f, 0.f, 0.f, 0.f);
#pragma unroll
        for (int i = 0; i < 8; ++i)
            outz[(size_t)i * 32768 + gid] = z;
    }
}

// ---------------------------------------------------------------------------
// Main: grid 256 = KQ(4) x 64 col-groups; 512 thr (8 waves; launch_bounds
// (512,2) -> 256-VGPR cap, the ~195-VGPR working set is register-resident,
// no spill, no 128-cap pipelining trap). Block (kq, cg): kt in [32kq,
// 32kq+32), cols [256cg, 256cg+256) as 8 tiles of 32. Wave w: 4 kt held
// ENTIRELY in registers (wreg 64 + tv 64 VGPR), one latency-amortized
// burst at start. Tile loop: ZERO global loads, B-frags = LDS BaseAll x
// reg Tcol via 2-instr packed-f32 cmul. Single-round epilogue per tile
// (both m-tiles, 2 barriers), f32 atomicAdd kq-combine (out zeroed in
// prep; 4 contributors, tolerance 0.5 >> reorder ulp).
__global__ void __launch_bounds__(512, 2) mv_main(
    const uint4* __restrict__ wexp,
    const float2* __restrict__ Tcol,
    const float2* __restrict__ A32,
    const float2* __restrict__ Abase,
    float* __restrict__ out) {
    __shared__ __align__(16) float2 BaseAll[NT * 512];   // 32 KB
    __shared__ __align__(16) float Red[16 * 1056];       // 66 KB (padded)

    const int t = threadIdx.x;
    const int kq = blockIdx.x & 3;
    const int cg = blockIdx.x >> 2;        // 0..63
    const int w = t >> 6;
    const int lw = t & 63;
    const int n = lw & 31;                 // column within 32-wide tile
    const int kh = lw >> 5;                // k-half of the fragment

    // ---- issue the two Base-table loads first, then the K-slice burst ----
    const int pg = kq * 512 + t;           // this block's p (512 of them)
    float2 ab0 = Abase[(size_t)(4 * cg) * P + pg];   // A_p^(256cg)
    float2 a32v = A32[pg];

    uint4 wreg[KTWV][2][2];                // [kk][mt][q]
    float2 tv[KTWV][8];                    // [kk][q*4+j]
    {
        const float2* tc = Tcol + n;
#pragma unroll
        for (int kk = 0; kk < KTWV; ++kk) {
            int kt = kq * 32 + w * KTWV + kk;
#pragma unroll
            for (int q = 0; q < 2; ++q) {
#pragma unroll
                for (int mt = 0; mt < 2; ++mt)
                    wreg[kk][mt][q] = wexp[(size_t)(((kt * 2 + q) * 2 + mt) * 64 + lw)];
                int pb = kt * 16 + q * 8 + kh * 4;
#pragma unroll
                for (int jj = 0; jj < 4; ++jj)
                    tv[kk][q * 4 + jj] = tc[(size_t)(pb + jj) * 32];
            }
        }
    }

    {   // ---- all 8 tile base columns upfront (7 pk-cmuls) ----
        float2 b = ab0;
#pragma unroll
        for (int j = 0; j < NT; ++j) {
            BaseAll[j * 512 + t] = b;      // A_p^(256cg + 32j)
            b = cmul_pk(b, a32v);
        }
    }
    __syncthreads();

    // epilogue index helpers (C/D layout m74: col = lane&31,
    // row = (r&3) + 8*(r>>2) + 4*(lane>>5))
    const int mtr = t >> 8;                // m-tile this thread reduces
    const int s = t & 255;
    const int cp = (s & 15) * 2;           // even column within 32

    for (int j = 0; j < NT; ++j) {
        f32x16 acc0, acc1;                 // [mt]
#pragma unroll
        for (int r = 0; r < 16; ++r) { acc0[r] = 0.f; acc1[r] = 0.f; }
        const float4* Bj = (const float4*)(BaseAll + j * 512);

#pragma unroll
        for (int kk = 0; kk < KTWV; ++kk) {
#pragma unroll
            for (int q = 0; q < 2; ++q) {
                int bi = (w * KTWV + kk) * 8 + q * 4 + kh * 2;
                float4 c0 = Bj[bi], c1 = Bj[bi + 1];
                uint32_t f[4];
                f[0] = packbf(cmul_pk(make_float2(c0.x, c0.y), tv[kk][q * 4 + 0]));
                f[1] = packbf(cmul_pk(make_float2(c0.z, c0.w), tv[kk][q * 4 + 1]));
                f[2] = packbf(cmul_pk(make_float2(c1.x, c1.y), tv[kk][q * 4 + 2]));
                f[3] = packbf(cmul_pk(make_float2(c1.z, c1.w), tv[kk][q * 4 + 3]));
                union { uint4 u; bf16x8 v; } F, A0, A1;
                F.u = make_uint4(f[0], f[1], f[2], f[3]);
                A0.u = wreg[kk][0][q];
                A1.u = wreg[kk][1][q];
                acc0 = __builtin_amdgcn_mfma_f32_32x32x16_bf16(A0.v, F.v, acc0, 0, 0, 0);
                acc1 = __builtin_amdgcn_mfma_f32_32x32x16_bf16(A1.v, F.v, acc1, 0, 0, 0);
            }
        }

        // ---- single-round epilogue: both m-tiles, 8-way K-reduce, atomics
#pragma unroll
        for (int r = 0; r < 16; ++r) {
            Red[(w * 2 + 0) * 1056 + r * 66 + lw] = acc0[r];
            Red[(w * 2 + 1) * 1056 + r * 66 + lw] = acc1[r];
        }
        __syncthreads();
#pragma unroll
        for (int ri = 0; ri < 2; ++ri) {
            int row = (s >> 4) + ri * 16;
            int rr = (row & 3) | ((row >> 3) << 2);
            int lane0 = cp + ((row >> 2) & 1) * 32;
            float sx = 0.f, sy = 0.f;
#pragma unroll
            for (int ww = 0; ww < 8; ++ww) {
                float2 v = *(const float2*)&Red[(ww * 2 + mtr) * 1056 + rr * 66 + lane0];
                sx += v.x;
                sy += v.y;
            }
            size_t oidx = (size_t)(mtr * 32 + row) * L + (size_t)cg * 256 + j * 32 + cp;
            atomicAdd(out + oidx, sx);
            atomicAdd(out + oidx + 1, sy);
        }
        __syncthreads();
    }
}

// ---------------------------------------------------------------------------
extern "C" void kernel_launch(void* const* d_in, const int* in_sizes, int n_in,
                              void* d_out, int out_size, void* d_ws, size_t ws_size,
                              hipStream_t stream) {
    const float* Ain = nullptr;
    const float* Win = nullptr;
    for (int i = 0; i < n_in; ++i) {
        if (in_sizes[i] == 2 * P) Ain = (const float*)d_in[i];
        else if (in_sizes[i] == 2 * HN * P) Win = (const float*)d_in[i];
    }
    if (!Ain) Ain = (const float*)d_in[0];
    if (!Win) Win = (const float*)d_in[1];
    (void)out_size; (void)ws_size;
    uint4* wexp = (uint4*)d_ws;                                  // 512 KB
    float2* tcol = (float2*)((char*)d_ws + 512 * 1024);          // +512 KB
    float2* a32 = (float2*)((char*)d_ws + 1024 * 1024);          // +16 KB
    float2* abase = (float2*)((char*)d_ws + 2 * 1024 * 1024);    // +4 MB
    mv_prep<<<128, 256, 0, stream>>>(Win, Ain, wexp, tcol, a32, abase,
                                     (float4*)d_out);
    mv_main<<<256, 512, 0, stream>>>(wexp, tcol, a32, abase, (float*)d_out);
}